// Round 4
// baseline (718.413 us; speedup 1.0000x reference)
//
#include <hip/hip_runtime.h>
#include <math.h>

// CasperNet R4: B=131072 rows, D=256, H=64 cascade, O=10.
// vs R3 (248us): spill persisted (VGPR capped at 64, ~100 live -> 227MB
// scratch writes). Fix: OUTPUT-split instead of k-split. Lane pair
// (2m,2m+1) shares row m; lane p owns interleaved neurons j=2t+p
// (32 accums) and outputs 2j+p (5 accums). Working set ~58 VGPRs -> fits
// the 64-reg budget with zero spill. Cascade broadcasts h via 1 shfl/step.
// All pair address deltas in LDS are 2-way same-bank (free per m136).

#define DIMD 256
#define DIMH 64
#define DIMO 10
#define DT   320
#define BLOCK 1024

__global__ __launch_bounds__(BLOCK, 4) void caspernet_kernel(
    const float* __restrict__ x,    // [B, 256]
    const float* __restrict__ Wh,   // [64, 320]
    const float* __restrict__ bh,   // [64]
    const float* __restrict__ Wo,   // [10, 320]
    const float* __restrict__ bo,   // [10]
    float* __restrict__ out,        // [B, 10]
    int B)
{
    __shared__ float sWhX[DIMH * DIMD];   // Wh[:,0:256]                64KB
    __shared__ float sWoX[DIMO * DIMD];   // Wo[:,0:256]                10KB
    __shared__ float sUtX[DIMH * DIMH];   // [i][p*32+t] = Wh[2t+p][256+i] 16KB
    __shared__ float sWtX[DIMH * 12];     // [i][p*6+j]  = Wo[2j+p][256+i]  3KB
    __shared__ float sBias[DIMH];         // [p*32+t] = bh[2t+p]
    __shared__ float sOb[16];             // [p*5+j]  = bo[2j+p]

    const int tid = threadIdx.x;

    // ---- stage weights into LDS (pair-interleaved layouts) ----
    {
        float4* dW = (float4*)sWhX;
        for (int idx = tid; idx < DIMH * (DIMD / 4); idx += BLOCK) {
            const int r = idx >> 6, c = idx & 63;
            dW[idx] = *reinterpret_cast<const float4*>(Wh + r * DT + c * 4);
        }
        float4* dO = (float4*)sWoX;
        for (int idx = tid; idx < DIMO * (DIMD / 4); idx += BLOCK) {
            const int r = idx >> 6, c = idx & 63;
            dO[idx] = *reinterpret_cast<const float4*>(Wo + r * DT + c * 4);
        }
        for (int idx = tid; idx < DIMH * DIMH; idx += BLOCK) {
            const int i = idx >> 6, m = idx & 63;
            const int p = m >> 5, t = m & 31;
            sUtX[idx] = Wh[(2 * t + p) * DT + DIMD + i];
        }
        for (int idx = tid; idx < DIMH * DIMO; idx += BLOCK) {
            const int i = idx / DIMO, m = idx % DIMO;
            const int p = m / 5, j = m % 5;
            sWtX[i * 12 + p * 6 + j] = Wo[(2 * j + p) * DT + DIMD + i];
        }
        if (tid < DIMH) {
            const int p = tid >> 5, t = tid & 31;
            sBias[tid] = bh[2 * t + p];
        }
        if (tid < DIMO) {
            const int p = tid / 5, j = tid % 5;
            sOb[p * 5 + j] = bo[2 * j + p];
        }
    }
    __syncthreads();

    const int gtid = blockIdx.x * BLOCK + tid;
    const int row  = gtid >> 1;     // 2 threads per row
    const int p    = gtid & 1;      // owns neurons 2t+p, outputs 2j+p
    if (row >= B) return;
    const float* xr = x + (size_t)row * DIMD;

    float a32[32];
    #pragma unroll
    for (int t = 0; t < 32; ++t) a32[t] = sBias[p * 32 + t];
    float ol[5];
    #pragma unroll
    for (int j = 0; j < 5; ++j) ol[j] = sOb[p * 5 + j];

    // ---- phase 1: full-k dot products for the 37 owned outputs ----
    // row (2t+p) base = sWhX + p*256 + t*512 ; offsets t*2048B fit ds imm.
    const float* wh0 = sWhX + p * DIMD;
    const float* wo0 = sWoX + p * DIMD;
    float4 cur = *reinterpret_cast<const float4*>(xr);
    for (int c = 0; c < 64; ++c) {
        // prefetch next chunk ((c+1)&63 wraps to a harmless L1-hit at c=63)
        const float4 nxt = *reinterpret_cast<const float4*>(xr + ((c + 1) & 63) * 4);
        const int off = c * 4;
        #pragma unroll
        for (int t = 0; t < 32; ++t) {
            const float4 w = *reinterpret_cast<const float4*>(wh0 + t * 512 + off);
            a32[t] = fmaf(cur.x, w.x, a32[t]);
            a32[t] = fmaf(cur.y, w.y, a32[t]);
            a32[t] = fmaf(cur.z, w.z, a32[t]);
            a32[t] = fmaf(cur.w, w.w, a32[t]);
        }
        #pragma unroll
        for (int j = 0; j < 5; ++j) {
            const float4 w = *reinterpret_cast<const float4*>(wo0 + j * 512 + off);
            ol[j] = fmaf(cur.x, w.x, ol[j]);
            ol[j] = fmaf(cur.y, w.y, ol[j]);
            ol[j] = fmaf(cur.z, w.z, ol[j]);
            ol[j] = fmaf(cur.w, w.w, ol[j]);
        }
        cur = nxt;
    }

    // ---- cascade: neuron i lives on lane (i&1) at index i>>1 ----
    const int pairbase = (tid & 63) & ~1;   // wave-local lane of pair lane0
    #pragma unroll
    for (int i = 0; i < DIMH; ++i) {
        const int tOwn = i >> 1;
        const int pOwn = i & 1;
        const float hraw = 1.0f / (1.0f + __expf(-a32[tOwn]));
        const float h = __shfl(hraw, pairbase + pOwn, 64);
        const float* ur = sUtX + i * 64 + p * 32;
        if ((i & 1) == 0) {
            // boundary t=i/2: neuron i+p -> update only on lane p==1
            const int tb = i >> 1;
            const float w = (p == 1) ? ur[tb] : 0.0f;
            a32[tb] = fmaf(w, h, a32[tb]);
        }
        #pragma unroll
        for (int t = (i + 2) >> 1; t < 32; ++t)    // 2t+p > i guaranteed
            a32[t] = fmaf(ur[t], h, a32[t]);
        const float* wr = sWtX + i * 12 + p * 6;
        #pragma unroll
        for (int j = 0; j < 5; ++j)
            ol[j] = fmaf(wr[j], h, ol[j]);
    }

    // ---- store: lane p writes cols 2j+p of its row ----
    float* orow = out + (size_t)row * DIMO + p;
    #pragma unroll
    for (int j = 0; j < 5; ++j) orow[2 * j] = ol[j];
}

extern "C" void kernel_launch(void* const* d_in, const int* in_sizes, int n_in,
                              void* d_out, int out_size, void* d_ws, size_t ws_size,
                              hipStream_t stream) {
    const float* x  = (const float*)d_in[0];
    const float* Wh = (const float*)d_in[1];
    const float* bh = (const float*)d_in[2];
    const float* Wo = (const float*)d_in[3];
    const float* bo = (const float*)d_in[4];
    float* out = (float*)d_out;

    const int B = in_sizes[0] / DIMD;                      // 131072
    const int threads_total = B * 2;
    const int grid = (threads_total + BLOCK - 1) / BLOCK;  // 256

    hipLaunchKernelGGL(caspernet_kernel, dim3(grid), dim3(BLOCK), 0, stream,
                       x, Wh, bh, Wo, bo, out, B);
}

// Round 5
// 180.705 us; speedup vs baseline: 3.9756x; 3.9756x over previous
//
#include <hip/hip_runtime.h>
#include <math.h>

// CasperNet R5: MFMA phase-1 + cascade in MFMA C-layout.
// B=131072, D=256, H=64, O=10.
// R2-R4 all spilled: 1024-thread blocks pin the compiler at 64 VGPRs while
// the per-lane row-accumulator design needs ~100. Fix is structural: the
// 74 per-row outputs now live as MFMA C-fragments (16 rows x 80 cols = 20
// VGPR/lane), and the cascade runs directly on that layout:
//   C layout (verified m89): col = lane&15, row = (lane>>4)*4 + reg.
//   step i: owner lane ci=i&15 holds pre-act of col i for 4 rows (reg ti=i>>4)
//   -> 4 shfl broadcasts within the 16-lane group -> sigmoid -> each lane
//   updates its owned cols {c,16+c,32+c,48+c} with a packed float4 U row
//   (weights for cols <= i staged as zero -> branch-free).
// Phase-1: x (A-frag) from global, W in LDS bf16 swizzled (k ^= (n&7)<<3).

#define DIMD 256
#define DIMH 64
#define DIMO 10
#define DT   320
#define NT   5       // 5 n-tiles of 16 = 80 cols (74 used)
#define TM   64      // rows per block (4 waves x 16)
#define BLOCK 256

typedef __attribute__((ext_vector_type(4))) float f32x4;
typedef __attribute__((ext_vector_type(8))) short bf16x8;

__device__ inline unsigned short f2bf(float f) {
    union { float f; unsigned u; } v; v.f = f;
    unsigned r = v.u + 0x7FFFu + ((v.u >> 16) & 1u);   // RNE
    return (unsigned short)(r >> 16);
}

__global__ __launch_bounds__(BLOCK, 4) void caspernet_kernel(
    const float* __restrict__ x,    // [B, 256]
    const float* __restrict__ Wh,   // [64, 320]
    const float* __restrict__ bh,   // [64]
    const float* __restrict__ Wo,   // [10, 320]
    const float* __restrict__ bo,   // [10]
    float* __restrict__ out,        // [B, 10]
    int B)
{
    __shared__ short sW[80 * DIMD];     // bf16 [n][k], k XOR-swizzled; 40KB
    __shared__ f32x4 sU4[DIMH * 16];    // [i][c]: U weights for cols c+16t; 16KB
    __shared__ float sWoh[DIMH * 16];   // [i][c]: head weight col c (0 pad); 4KB
    __shared__ float sBias[80];

    const int tid = threadIdx.x;

    // ---- stage W1 = [Wh_x; Wo_x] as bf16, swizzled ----
    for (int idx = tid; idx < 80 * 64; idx += BLOCK) {   // 80 rows x 64 float4
        const int n = idx >> 6, k0 = (idx & 63) * 4;
        float4 v = make_float4(0.f, 0.f, 0.f, 0.f);
        if (n < DIMH)      v = *reinterpret_cast<const float4*>(Wh + n * DT + k0);
        else if (n < 74)   v = *reinterpret_cast<const float4*>(Wo + (n - 64) * DT + k0);
        const int kz = k0 ^ ((n & 7) << 3);
        short* d = sW + n * DIMD + kz;
        d[0] = (short)f2bf(v.x); d[1] = (short)f2bf(v.y);
        d[2] = (short)f2bf(v.z); d[3] = (short)f2bf(v.w);
    }
    // ---- stage cascade weights (pre-masked) + head + bias ----
    for (int idx = tid; idx < DIMH * 16; idx += BLOCK) {
        const int i = idx >> 4, c = idx & 15;
        f32x4 u;
        u[0] = (c      > i) ? Wh[(c     ) * DT + DIMD + i] : 0.f;
        u[1] = (16 + c > i) ? Wh[(16 + c) * DT + DIMD + i] : 0.f;
        u[2] = (32 + c > i) ? Wh[(32 + c) * DT + DIMD + i] : 0.f;
        u[3] = (48 + c > i) ? Wh[(48 + c) * DT + DIMD + i] : 0.f;
        sU4[idx] = u;
        sWoh[idx] = (c < DIMO) ? Wo[c * DT + DIMD + i] : 0.f;
    }
    if (tid < 80) sBias[tid] = (tid < 64) ? bh[tid] : ((tid < 74) ? bo[tid - 64] : 0.f);
    __syncthreads();

    const int l  = tid & 63;
    const int w  = tid >> 6;          // wave id 0..3 -> rows w*16..w*16+15
    const int lm = l & 15, lg = l >> 4;

    // ---- phase 1: acc[t] = x-tile @ W1^T (tile t) ----
    const size_t rowA = (size_t)blockIdx.x * TM + w * 16 + lm;   // A-frag row
    const float* xr = x + rowA * DIMD + lg * 8;

    f32x4 acc[NT];
    #pragma unroll
    for (int t = 0; t < NT; ++t) acc[t] = (f32x4){0.f, 0.f, 0.f, 0.f};

    #pragma unroll
    for (int ks = 0; ks < 8; ++ks) {
        const float4 xa = *reinterpret_cast<const float4*>(xr + ks * 32);
        const float4 xb = *reinterpret_cast<const float4*>(xr + ks * 32 + 4);
        bf16x8 af;
        af[0] = (short)f2bf(xa.x); af[1] = (short)f2bf(xa.y);
        af[2] = (short)f2bf(xa.z); af[3] = (short)f2bf(xa.w);
        af[4] = (short)f2bf(xb.x); af[5] = (short)f2bf(xb.y);
        af[6] = (short)f2bf(xb.z); af[7] = (short)f2bf(xb.w);
        #pragma unroll
        for (int t = 0; t < NT; ++t) {
            const int n = t * 16 + lm;
            const int kz = (lg * 8 + ks * 32) ^ ((n & 7) << 3);
            const bf16x8 bf = *reinterpret_cast<const bf16x8*>(sW + n * DIMD + kz);
            acc[t] = __builtin_amdgcn_mfma_f32_16x16x32_bf16(af, bf, acc[t], 0, 0, 0);
        }
    }
    // bias (per output column)
    #pragma unroll
    for (int t = 0; t < NT; ++t) {
        const float bt = sBias[t * 16 + lm];
        acc[t][0] += bt; acc[t][1] += bt; acc[t][2] += bt; acc[t][3] += bt;
    }

    // ---- phase 2: cascade on the C-layout ----
    const int gbase = l & 48;         // 16-lane group base
    #pragma unroll
    for (int i = 0; i < DIMH; ++i) {
        const int ti = i >> 4, ci = i & 15;
        float s0 = __shfl(acc[ti][0], gbase | ci, 64);
        float s1 = __shfl(acc[ti][1], gbase | ci, 64);
        float s2 = __shfl(acc[ti][2], gbase | ci, 64);
        float s3 = __shfl(acc[ti][3], gbase | ci, 64);
        const float h0 = 1.f / (1.f + __expf(-s0));
        const float h1 = 1.f / (1.f + __expf(-s1));
        const float h2 = 1.f / (1.f + __expf(-s2));
        const float h3 = 1.f / (1.f + __expf(-s3));
        const f32x4 u = sU4[i * 16 + lm];
        const float wo = sWoh[i * 16 + lm];
        #pragma unroll
        for (int t = ti; t < 4; ++t) {      // cols <= i have zero weights
            acc[t][0] = fmaf(u[t], h0, acc[t][0]);
            acc[t][1] = fmaf(u[t], h1, acc[t][1]);
            acc[t][2] = fmaf(u[t], h2, acc[t][2]);
            acc[t][3] = fmaf(u[t], h3, acc[t][3]);
        }
        acc[4][0] = fmaf(wo, h0, acc[4][0]);
        acc[4][1] = fmaf(wo, h1, acc[4][1]);
        acc[4][2] = fmaf(wo, h2, acc[4][2]);
        acc[4][3] = fmaf(wo, h3, acc[4][3]);
    }

    // ---- store head tile (cols 64..73 = C-tile 4, cols lm<10) ----
    if (lm < DIMO) {
        const size_t orow0 = (size_t)blockIdx.x * TM + w * 16 + lg * 4;
        #pragma unroll
        for (int r = 0; r < 4; ++r)
            out[(orow0 + r) * DIMO + lm] = acc[4][r];
    }
}

extern "C" void kernel_launch(void* const* d_in, const int* in_sizes, int n_in,
                              void* d_out, int out_size, void* d_ws, size_t ws_size,
                              hipStream_t stream) {
    const float* x  = (const float*)d_in[0];
    const float* Wh = (const float*)d_in[1];
    const float* bh = (const float*)d_in[2];
    const float* Wo = (const float*)d_in[3];
    const float* bo = (const float*)d_in[4];
    float* out = (float*)d_out;

    const int B = in_sizes[0] / DIMD;      // 131072
    const int grid = B / TM;               // 2048

    hipLaunchKernelGGL(caspernet_kernel, dim3(grid), dim3(BLOCK), 0, stream,
                       x, Wh, bh, Wo, bo, out, B);
}